// Round 4
// baseline (147.192 us; speedup 1.0000x reference)
//
#include <hip/hip_runtime.h>

// Problem constants: B=2, N=2048, F_IN=128, H=8, F=32
constexpr int Bv  = 2;
constexpr int Nv  = 2048;
constexpr int FIN = 128;
constexpr int Hn  = 8;
constexpr int Fv  = 32;
constexpr int NROW = Bv * Nv;      // 4096 rows
constexpr int S    = NROW * Hn;    // 32768 floats per PQ array

// ---------------------------------------------------------------------------
// prep: (1) wa[which][k][h] = sum_f w[k,h*F+f]*a[which*F+f] in LDS,
//       (2) s_j/s_i per (row,h), (3) write Pj=exp(sj), Qj=exp(.2 sj),
//       Pi=exp(si), Qi=exp(.2 si).  pq layout: [Pj | Qj | Pi | Qi], each S.
// grid: NROW/32 = 128 blocks x 256
// ---------------------------------------------------------------------------
__global__ __launch_bounds__(256) void prep_kernel(
    const float* __restrict__ w, const float* __restrict__ a,
    const float* __restrict__ x, float* __restrict__ pq) {
    __shared__ float wa[2 * FIN * Hn];   // 2048 floats = 8 KB
    const int tid = threadIdx.x;

    for (int e = tid; e < 2 * FIN * Hn; e += 256) {
        const int which = e >> 10;
        const int k     = (e >> 3) & (FIN - 1);
        const int h     = e & (Hn - 1);
        const float* ap = a + which * Fv;
        const float* wp = w + (size_t)k * (Fv * Hn) + h * Fv;
        float s = 0.f;
        #pragma unroll
        for (int f = 0; f < Fv; ++f) s = fmaf(wp[f], ap[f], s);
        wa[e] = s;
    }
    __syncthreads();

    const int row = blockIdx.x * 32 + (tid >> 3);
    const int h   = tid & (Hn - 1);
    const float* xr = x + (size_t)row * FIN;
    float sj = 0.f, si = 0.f;
    #pragma unroll 4
    for (int k = 0; k < FIN; ++k) {
        const float xv = xr[k];
        sj = fmaf(xv, wa[k * Hn + h], sj);
        si = fmaf(xv, wa[FIN * Hn + k * Hn + h], si);
    }
    const int idx = row * Hn + h;
    pq[idx]         = __expf(sj);
    pq[S + idx]     = __expf(0.2f * sj);
    pq[2 * S + idx] = __expf(si);
    pq[3 * S + idx] = __expf(0.2f * si);
}

// ---------------------------------------------------------------------------
// main: one block per output row (b,i).
//   e[i,j,h] = max(Pi[h]*Pj[j,h], Qi[h]*Qj[j,h])   (== exp(lrelu(si+sj)))
//   phase 1: norm[h] = sum_j g*e   (skip loads where g==0; ~5% dense)
//   phase 2: out = e * (1/norm), float4-slot mapping for contiguous stores
// ---------------------------------------------------------------------------
__global__ __launch_bounds__(256) void attn_out_kernel(
    const float* __restrict__ g, const float* __restrict__ pq,
    float* __restrict__ out) {
    const int row = blockIdx.x;        // b*N + i
    const int b   = row >> 11;         // N = 2048
    const int tid = threadIdx.x;

    const float* __restrict__ Pip = pq + 2 * S + row * Hn;
    const float* __restrict__ Qip = pq + 3 * S + row * Hn;
    float pi[Hn], qi[Hn];
    #pragma unroll
    for (int h = 0; h < Hn; ++h) { pi[h] = Pip[h]; qi[h] = Qip[h]; }

    const float* __restrict__ grow = g + (size_t)row * Nv;
    const float4* __restrict__ Pj4 = (const float4*)(pq + (size_t)b * Nv * Hn);
    const float4* __restrict__ Qj4 = (const float4*)(pq + S + (size_t)b * Nv * Hn);

    float norm[Hn];
    #pragma unroll
    for (int h = 0; h < Hn; ++h) norm[h] = 0.f;

    // ---- phase 1: sparse-aware norm accumulation ----
    for (int j = tid; j < Nv; j += 256) {
        const float gv = __builtin_nontemporal_load(&grow[j]);
        if (gv != 0.f) {               // exec-masked: ~3/64 lanes active
            const float4 p0 = Pj4[2 * j], p1 = Pj4[2 * j + 1];
            const float4 q0 = Qj4[2 * j], q1 = Qj4[2 * j + 1];
            const float pj[Hn] = {p0.x, p0.y, p0.z, p0.w, p1.x, p1.y, p1.z, p1.w};
            const float qj[Hn] = {q0.x, q0.y, q0.z, q0.w, q1.x, q1.y, q1.z, q1.w};
            #pragma unroll
            for (int h = 0; h < Hn; ++h)
                norm[h] = fmaf(gv, fmaxf(pi[h] * pj[h], qi[h] * qj[h]), norm[h]);
        }
    }

    // ---- block reduction (4 waves) ----
    __shared__ float red[4][Hn];
    __shared__ float rnorm_s[Hn];
    const int lane = tid & 63, wv = tid >> 6;
    #pragma unroll
    for (int h = 0; h < Hn; ++h) {
        float v = norm[h];
        #pragma unroll
        for (int off = 32; off > 0; off >>= 1) v += __shfl_down(v, off);
        if (lane == 0) red[wv][h] = v;
    }
    __syncthreads();
    if (tid < Hn)
        rnorm_s[tid] = 1.0f / (red[0][tid] + red[1][tid] + red[2][tid] + red[3][tid]);
    __syncthreads();

    float rn[Hn];
    #pragma unroll
    for (int h = 0; h < Hn; ++h) rn[h] = rnorm_s[h];

    // per-thread half-of-heads selection: p&1 == tid&1 (loop-invariant)
    float pis[4], qis[4], rns[4];
    #pragma unroll
    for (int c = 0; c < 4; ++c) {      // static indices, cndmask select
        pis[c] = (tid & 1) ? pi[4 + c] : pi[c];
        qis[c] = (tid & 1) ? qi[4 + c] : qi[c];
        rns[c] = (tid & 1) ? rn[4 + c] : rn[c];
    }

    // ---- phase 2: slot p in [0, 2N): j = p>>1, heads (p&1)*4 .. +3 ----
    // lane writes 16 B at offset p*16: one fully-contiguous 1KB store/instr
    float4* __restrict__ orow = (float4*)(out + (size_t)row * Nv * Hn);
    for (int p = tid; p < 2 * Nv; p += 256) {
        const float4 pj = Pj4[p];
        const float4 qj = Qj4[p];
        float4 o;
        o.x = fmaxf(pis[0] * pj.x, qis[0] * qj.x) * rns[0];
        o.y = fmaxf(pis[1] * pj.y, qis[1] * qj.y) * rns[1];
        o.z = fmaxf(pis[2] * pj.z, qis[2] * qj.z) * rns[2];
        o.w = fmaxf(pis[3] * pj.w, qis[3] * qj.w) * rns[3];
        orow[p] = o;
    }
}

// ---------------------------------------------------------------------------
extern "C" void kernel_launch(void* const* d_in, const int* in_sizes, int n_in,
                              void* d_out, int out_size, void* d_ws, size_t ws_size,
                              hipStream_t stream) {
    const float* g = (const float*)d_in[0];   // (B,N,N)
    const float* x = (const float*)d_in[1];   // (B,N,F_IN)
    const float* w = (const float*)d_in[2];   // (F_IN, F*H)
    const float* a = (const float*)d_in[3];   // (2F,)

    float* pq  = (float*)d_ws;                // 4*S floats = 512 KB
    float* out = (float*)d_out;               // (B,N,N,H) fp32

    prep_kernel<<<NROW / 32, 256, 0, stream>>>(w, a, x, pq);
    attn_out_kernel<<<NROW, 256, 0, stream>>>(g, pq, out);
}

// Round 5
// 136.760 us; speedup vs baseline: 1.0763x; 1.0763x over previous
//
#include <hip/hip_runtime.h>

// Problem constants: B=2, N=2048, F_IN=128, H=8, F=32
constexpr int Bv  = 2;
constexpr int Nv  = 2048;
constexpr int FIN = 128;
constexpr int Hn  = 8;
constexpr int Fv  = 32;
constexpr int NROW = Bv * Nv;      // 4096 rows
constexpr int S    = NROW * Hn;    // 32768 floats per PQ array

// ---------------------------------------------------------------------------
// prep: wa in LDS, then s_j/s_i per (row,h), write Pj=exp(sj), Qj=exp(.2 sj),
// Pi=exp(si), Qi=exp(.2 si).  pq layout: [Pj | Qj | Pi | Qi], each S floats.
// ---------------------------------------------------------------------------
__global__ __launch_bounds__(256) void prep_kernel(
    const float* __restrict__ w, const float* __restrict__ a,
    const float* __restrict__ x, float* __restrict__ pq) {
    __shared__ float wa[2 * FIN * Hn];   // 2048 floats = 8 KB
    const int tid = threadIdx.x;

    for (int e = tid; e < 2 * FIN * Hn; e += 256) {
        const int which = e >> 10;
        const int k     = (e >> 3) & (FIN - 1);
        const int h     = e & (Hn - 1);
        const float* ap = a + which * Fv;
        const float* wp = w + (size_t)k * (Fv * Hn) + h * Fv;
        float s = 0.f;
        #pragma unroll
        for (int f = 0; f < Fv; ++f) s = fmaf(wp[f], ap[f], s);
        wa[e] = s;
    }
    __syncthreads();

    const int row = blockIdx.x * 32 + (tid >> 3);
    const int h   = tid & (Hn - 1);
    const float* xr = x + (size_t)row * FIN;
    float sj = 0.f, si = 0.f;
    #pragma unroll 4
    for (int k = 0; k < FIN; ++k) {
        const float xv = xr[k];
        sj = fmaf(xv, wa[k * Hn + h], sj);
        si = fmaf(xv, wa[FIN * Hn + k * Hn + h], si);
    }
    const int idx = row * Hn + h;
    pq[idx]         = __expf(sj);
    pq[S + idx]     = __expf(0.2f * sj);
    pq[2 * S + idx] = __expf(si);
    pq[3 * S + idx] = __expf(0.2f * si);
}

// ---------------------------------------------------------------------------
// main: one block per output row (b,i). BRANCHLESS.
//   e[i,j,h] = max(Pi[h]*Pj[j,h], Qi[h]*Qj[j,h])  == exp(lrelu(si+sj))
//   phase 1: norm[h] = sum_j g*e   (unconditional loads, full unroll, ILP)
//   phase 2: out = max(pi*rn*Pj, qi*rn*Qj), slot-mapped contiguous stores
// ---------------------------------------------------------------------------
__global__ __launch_bounds__(256) void attn_out_kernel(
    const float* __restrict__ g, const float* __restrict__ pq,
    float* __restrict__ out) {
    const int row = blockIdx.x;        // b*N + i
    const int b   = row >> 11;         // N = 2048
    const int tid = threadIdx.x;

    const float* __restrict__ Pip = pq + 2 * S + row * Hn;
    const float* __restrict__ Qip = pq + 3 * S + row * Hn;
    float pi[Hn], qi[Hn];
    #pragma unroll
    for (int h = 0; h < Hn; ++h) { pi[h] = Pip[h]; qi[h] = Qip[h]; }

    const float* __restrict__ grow = g + (size_t)row * Nv;
    const float4* __restrict__ Pj4 = (const float4*)(pq + (size_t)b * Nv * Hn);
    const float4* __restrict__ Qj4 = (const float4*)(pq + S + (size_t)b * Nv * Hn);

    float norm[Hn];
    #pragma unroll
    for (int h = 0; h < Hn; ++h) norm[h] = 0.f;

    // ---- phase 1: branchless norm accumulation, fully unrolled (8 iters) ----
    #pragma unroll
    for (int it = 0; it < Nv / 256; ++it) {
        const int j = tid + it * 256;
        const float gv = grow[j];
        const float4 p0 = Pj4[2 * j], p1 = Pj4[2 * j + 1];
        const float4 q0 = Qj4[2 * j], q1 = Qj4[2 * j + 1];
        norm[0] = fmaf(gv, fmaxf(pi[0] * p0.x, qi[0] * q0.x), norm[0]);
        norm[1] = fmaf(gv, fmaxf(pi[1] * p0.y, qi[1] * q0.y), norm[1]);
        norm[2] = fmaf(gv, fmaxf(pi[2] * p0.z, qi[2] * q0.z), norm[2]);
        norm[3] = fmaf(gv, fmaxf(pi[3] * p0.w, qi[3] * q0.w), norm[3]);
        norm[4] = fmaf(gv, fmaxf(pi[4] * p1.x, qi[4] * q1.x), norm[4]);
        norm[5] = fmaf(gv, fmaxf(pi[5] * p1.y, qi[5] * q1.y), norm[5]);
        norm[6] = fmaf(gv, fmaxf(pi[6] * p1.z, qi[6] * q1.z), norm[6]);
        norm[7] = fmaf(gv, fmaxf(pi[7] * p1.w, qi[7] * q1.w), norm[7]);
    }

    // ---- block reduction (4 waves) ----
    __shared__ float red[4][Hn];
    __shared__ float rnorm_s[Hn];
    const int lane = tid & 63, wv = tid >> 6;
    #pragma unroll
    for (int h = 0; h < Hn; ++h) {
        float v = norm[h];
        #pragma unroll
        for (int off = 32; off > 0; off >>= 1) v += __shfl_down(v, off);
        if (lane == 0) red[wv][h] = v;
    }
    __syncthreads();
    if (tid < Hn)
        rnorm_s[tid] = 1.0f / (red[0][tid] + red[1][tid] + red[2][tid] + red[3][tid]);
    __syncthreads();

    // per-thread head-half selection (p&1 == tid&1, loop-invariant),
    // with 1/norm folded in: out = max(pr*Pj, qr*Qj)
    float pr[4], qr[4];
    #pragma unroll
    for (int c = 0; c < 4; ++c) {      // static indices only (no scratch)
        const float rv = (tid & 1) ? rnorm_s[4 + c] : rnorm_s[c];
        const float pv = (tid & 1) ? pi[4 + c] : pi[c];
        const float qv = (tid & 1) ? qi[4 + c] : qi[c];
        pr[c] = pv * rv;
        qr[c] = qv * rv;
    }

    // ---- phase 2: slot p in [0,2N): j = p>>1, heads (p&1)*4 .. +3 ----
    // each wave store = 64 lanes x 16 B fully contiguous (1 KB)
    float4* __restrict__ orow = (float4*)(out + (size_t)row * Nv * Hn);
    #pragma unroll 4
    for (int it = 0; it < 2 * Nv / 256; ++it) {
        const int p = tid + it * 256;
        const float4 pj = Pj4[p];
        const float4 qj = Qj4[p];
        float4 o;
        o.x = fmaxf(pr[0] * pj.x, qr[0] * qj.x);
        o.y = fmaxf(pr[1] * pj.y, qr[1] * qj.y);
        o.z = fmaxf(pr[2] * pj.z, qr[2] * qj.z);
        o.w = fmaxf(pr[3] * pj.w, qr[3] * qj.w);
        orow[p] = o;
    }
}

// ---------------------------------------------------------------------------
extern "C" void kernel_launch(void* const* d_in, const int* in_sizes, int n_in,
                              void* d_out, int out_size, void* d_ws, size_t ws_size,
                              hipStream_t stream) {
    const float* g = (const float*)d_in[0];   // (B,N,N)
    const float* x = (const float*)d_in[1];   // (B,N,F_IN)
    const float* w = (const float*)d_in[2];   // (F_IN, F*H)
    const float* a = (const float*)d_in[3];   // (2F,)

    float* pq  = (float*)d_ws;                // 4*S floats = 512 KB
    float* out = (float*)d_out;               // (B,N,N,H) fp32

    prep_kernel<<<NROW / 32, 256, 0, stream>>>(w, a, x, pq);
    attn_out_kernel<<<NROW, 256, 0, stream>>>(g, pq, out);
}

// Round 7
// 91.395 us; speedup vs baseline: 1.6105x; 1.4964x over previous
//
#include <hip/hip_runtime.h>

// Problem constants: B=2, N=2048, F_IN=128, H=8, F=32
constexpr int Bv  = 2;
constexpr int Nv  = 2048;
constexpr int FIN = 128;
constexpr int Hn  = 8;
constexpr int Fv  = 32;
constexpr int NROW = Bv * Nv;      // 4096 rows
constexpr int S    = NROW * Hn;    // 32768 floats per PQ array

typedef float v4f __attribute__((ext_vector_type(4)));

// ---------------------------------------------------------------------------
// prep: wa in LDS, then s_j/s_i per (row,h); write Pj=exp(sj), Qj=exp(.2 sj),
// Pi=exp(si), Qi=exp(.2 si).  pq layout: [Pj | Qj | Pi | Qi], each S floats.
// ---------------------------------------------------------------------------
__global__ __launch_bounds__(256) void prep_kernel(
    const float* __restrict__ w, const float* __restrict__ a,
    const float* __restrict__ x, float* __restrict__ pq) {
    __shared__ float wa[2 * FIN * Hn];   // 2048 floats = 8 KB
    const int tid = threadIdx.x;

    for (int e = tid; e < 2 * FIN * Hn; e += 256) {
        const int which = e >> 10;
        const int k     = (e >> 3) & (FIN - 1);
        const int h     = e & (Hn - 1);
        const float* ap = a + which * Fv;
        const float* wp = w + (size_t)k * (Fv * Hn) + h * Fv;
        float s = 0.f;
        #pragma unroll
        for (int f = 0; f < Fv; ++f) s = fmaf(wp[f], ap[f], s);
        wa[e] = s;
    }
    __syncthreads();

    const int row = blockIdx.x * 32 + (tid >> 3);
    const int h   = tid & (Hn - 1);
    const float* xr = x + (size_t)row * FIN;
    float sj = 0.f, si = 0.f;
    #pragma unroll 4
    for (int k = 0; k < FIN; ++k) {
        const float xv = xr[k];
        sj = fmaf(xv, wa[k * Hn + h], sj);
        si = fmaf(xv, wa[FIN * Hn + k * Hn + h], si);
    }
    const int idx = row * Hn + h;
    pq[idx]         = __expf(sj);
    pq[S + idx]     = __expf(0.2f * sj);
    pq[2 * S + idx] = __expf(si);
    pq[3 * S + idx] = __expf(0.2f * si);
}

// ---------------------------------------------------------------------------
// norm: 2048 blocks, 2 rows per block (halves PQ re-read traffic).
//   n[row][h] = sum_j g[row,j] * max(Pi*Pj, Qi*Qj)
//   writes tbl[row][0..7] = Pi[h]/n[h], tbl[row][8..15] = Qi[h]/n[h]
// ---------------------------------------------------------------------------
__global__ __launch_bounds__(256) void norm_kernel(
    const float* __restrict__ g, const float* __restrict__ pq,
    float* __restrict__ tbl) {
    const int row0 = blockIdx.x * 2;
    const int row1 = row0 + 1;
    const int b    = row0 >> 11;       // rows of a pair share a batch
    const int tid  = threadIdx.x;

    float pi0[Hn], qi0[Hn], pi1[Hn], qi1[Hn];
    #pragma unroll
    for (int h = 0; h < Hn; ++h) {
        pi0[h] = pq[2 * S + row0 * Hn + h];
        qi0[h] = pq[3 * S + row0 * Hn + h];
        pi1[h] = pq[2 * S + row1 * Hn + h];
        qi1[h] = pq[3 * S + row1 * Hn + h];
    }

    const float* __restrict__ g0 = g + (size_t)row0 * Nv;
    const float* __restrict__ g1 = g + (size_t)row1 * Nv;
    const float4* __restrict__ Pj4 = (const float4*)(pq + (size_t)b * Nv * Hn);
    const float4* __restrict__ Qj4 = (const float4*)(pq + S + (size_t)b * Nv * Hn);

    float n0[Hn], n1[Hn];
    #pragma unroll
    for (int h = 0; h < Hn; ++h) { n0[h] = 0.f; n1[h] = 0.f; }

    #pragma unroll 2
    for (int it = 0; it < Nv / 256; ++it) {
        const int j = tid + it * 256;
        const float gv0 = __builtin_nontemporal_load(&g0[j]);
        const float gv1 = __builtin_nontemporal_load(&g1[j]);
        const float4 p0 = Pj4[2 * j], p1 = Pj4[2 * j + 1];
        const float4 q0 = Qj4[2 * j], q1 = Qj4[2 * j + 1];
        const float pj[Hn] = {p0.x, p0.y, p0.z, p0.w, p1.x, p1.y, p1.z, p1.w};
        const float qj[Hn] = {q0.x, q0.y, q0.z, q0.w, q1.x, q1.y, q1.z, q1.w};
        #pragma unroll
        for (int h = 0; h < Hn; ++h) {
            n0[h] = fmaf(gv0, fmaxf(pi0[h] * pj[h], qi0[h] * qj[h]), n0[h]);
            n1[h] = fmaf(gv1, fmaxf(pi1[h] * pj[h], qi1[h] * qj[h]), n1[h]);
        }
    }

    // block reduction of 16 accumulators
    __shared__ float red[4][16];
    const int lane = tid & 63, wv = tid >> 6;
    #pragma unroll
    for (int h = 0; h < Hn; ++h) {
        float v = n0[h];
        #pragma unroll
        for (int off = 32; off > 0; off >>= 1) v += __shfl_down(v, off);
        if (lane == 0) red[wv][h] = v;
    }
    #pragma unroll
    for (int h = 0; h < Hn; ++h) {
        float v = n1[h];
        #pragma unroll
        for (int off = 32; off > 0; off >>= 1) v += __shfl_down(v, off);
        if (lane == 0) red[wv][8 + h] = v;
    }
    __syncthreads();
    if (tid < 16) {
        const int r = tid >> 3, h = tid & 7;
        const int row = row0 + r;
        const float nsum = red[0][tid] + red[1][tid] + red[2][tid] + red[3][tid];
        const float rn = 1.0f / nsum;    // n > 0 (diag of g is 1, e > 0)
        const float piv = pq[2 * S + row * Hn + h];
        const float qiv = pq[3 * S + row * Hn + h];
        tbl[row * 16 + h]     = piv * rn;
        tbl[row * 16 + 8 + h] = qiv * rn;
    }
}

// ---------------------------------------------------------------------------
// out: pure stream. 8192 blocks; block = (row, j-half). Slot s in [0,4096)
// per row: j = s>>1, heads (s&1)*4..+3.  out = max(pr*Pj, qr*Qj).
// Stores are nontemporal (evict-first) so they don't thrash PQ out of L2.
// ---------------------------------------------------------------------------
__global__ __launch_bounds__(256) void out_kernel(
    const float* __restrict__ pq, const float* __restrict__ tbl,
    float* __restrict__ out) {
    const int bid  = blockIdx.x;        // 0..8191
    const int row  = bid >> 1;
    const int half = bid & 1;
    const int b    = row >> 11;
    const int tid  = threadIdx.x;
    const int hh   = tid & 1;           // head-half for every slot this thread touches

    const float4 prv = *(const float4*)(tbl + row * 16 + hh * 4);
    const float4 qrv = *(const float4*)(tbl + row * 16 + 8 + hh * 4);

    const float4* __restrict__ Pb = (const float4*)(pq + (size_t)b * Nv * Hn);
    const float4* __restrict__ Qb = (const float4*)(pq + S + (size_t)b * Nv * Hn);
    float* __restrict__ orow = out + (size_t)row * Nv * Hn;

    const int base = half * 2048 + tid;
    #pragma unroll
    for (int it = 0; it < 8; ++it) {
        const int s = base + it * 256;
        const float4 pj = Pb[s];
        const float4 qj = Qb[s];
        v4f o;
        o.x = fmaxf(prv.x * pj.x, qrv.x * qj.x);
        o.y = fmaxf(prv.y * pj.y, qrv.y * qj.y);
        o.z = fmaxf(prv.z * pj.z, qrv.z * qj.z);
        o.w = fmaxf(prv.w * pj.w, qrv.w * qj.w);
        __builtin_nontemporal_store(o, (v4f*)(orow + (size_t)s * 4));
    }
}

// ---------------------------------------------------------------------------
extern "C" void kernel_launch(void* const* d_in, const int* in_sizes, int n_in,
                              void* d_out, int out_size, void* d_ws, size_t ws_size,
                              hipStream_t stream) {
    const float* g = (const float*)d_in[0];   // (B,N,N)
    const float* x = (const float*)d_in[1];   // (B,N,F_IN)
    const float* w = (const float*)d_in[2];   // (F_IN, F*H)
    const float* a = (const float*)d_in[3];   // (2F,)

    float* pq  = (float*)d_ws;                // 4*S floats = 512 KB
    float* tbl = pq + 4 * S;                  // 4096*16 floats = 256 KB
    float* out = (float*)d_out;               // (B,N,N,H) fp32

    prep_kernel<<<NROW / 32, 256, 0, stream>>>(w, a, x, pq);
    norm_kernel<<<NROW / 2, 256, 0, stream>>>(g, pq, tbl);
    out_kernel<<<NROW * 2, 256, 0, stream>>>(pq, tbl, out);
}